// Round 4
// baseline (1508.181 us; speedup 1.0000x reference)
//
#include <hip/hip_runtime.h>
#include <hip/hip_bf16.h>

typedef unsigned short u16;
typedef __bf16 bf16x8 __attribute__((ext_vector_type(8)));
typedef float  floatx4 __attribute__((ext_vector_type(4)));
typedef u16    u16x8   __attribute__((ext_vector_type(8)));

#define B_    16
#define C_    384
#define H_    64
#define W_    64
#define TOK   65536      // B*H*W tokens
#define N3    1152       // 3*C
#define CHID  1536       // 4*C
#define HD    48         // head dim
#define NCHUNK 8
#define BPC   (B_ / NCHUNK)       // 2 batches per chunk
#define CTOK  (TOK / NCHUNK)      // 8192 tokens per chunk
#define CWIN  (CTOK / 64)         // 128 windows per chunk

__device__ __forceinline__ float u2f(u16 u) { return __uint_as_float(((unsigned)u) << 16); }
__device__ __forceinline__ u16   f2u(float f) { __bf16 b = (__bf16)f; return *reinterpret_cast<u16*>(&b); }
__device__ __forceinline__ float gelu_f(float v) { return 0.5f * v * (1.0f + erff(v * 0.70710678118654752f)); }

// Async global->LDS, 16B per lane. LDS dest is wave-uniform base + lane*16
// (m104/m108); global src is per-lane.
__device__ __forceinline__ void gload_lds16(const u16* g, u16* l) {
  __builtin_amdgcn_global_load_lds(
      (const __attribute__((address_space(1))) void*)g,
      (__attribute__((address_space(3))) void*)l,
      16, 0, 0);
}

// ---------------------------------------------------------------------------
// roll(-4,-4) + window partition + LayerNorm1 for BPC batches (fp32 input).
// Token layout: t = (b_local*64 + (h/8)*8 + (w/8))*64 + (h%8)*8 + (w%8),
// h/w in rolled coords; rolled (h,w) reads original ((h+4)%64,(w+4)%64).
// ---------------------------------------------------------------------------
__global__ __launch_bounds__(256) void ln1_kernel(const float* __restrict__ x,
                                                  const float* __restrict__ g,
                                                  const float* __restrict__ bta,
                                                  u16* __restrict__ wins) {
  __shared__ u16 tile[64][C_ + 2];
  __shared__ float psum[4][64], psq[4][64], mean_s[64], rstd_s[64];
  int tid = threadIdx.x;
  int bb = blockIdx.x >> 6;        // local batch
  int h  = blockIdx.x & 63;        // rolled row
  int h0 = (h + 4) & 63;           // original row
  for (int i = 0; i < 96; ++i) {
    int idx = i * 256 + tid;
    int ch = idx >> 6, wr = idx & 63;
    int w0 = (wr + 4) & 63;
    size_t xi = ((size_t)(bb * C_ + ch) << 12) + (h0 << 6) + w0;
    tile[wr][ch] = f2u(x[xi]);
  }
  __syncthreads();
  {
    int s = tid >> 6, p = tid & 63;
    float sm = 0.f, sq = 0.f;
    for (int ii = 0; ii < 96; ++ii) {
      float v = u2f(tile[p][s * 96 + ii]);
      sm += v; sq += v * v;
    }
    psum[s][p] = sm; psq[s][p] = sq;
  }
  __syncthreads();
  if (tid < 64) {
    float m  = psum[0][tid] + psum[1][tid] + psum[2][tid] + psum[3][tid];
    float q2 = psq[0][tid] + psq[1][tid] + psq[2][tid] + psq[3][tid];
    m /= (float)C_;
    float var = q2 / (float)C_ - m * m;
    mean_s[tid] = m;
    rstd_s[tid] = rsqrtf(var + 1e-5f);
  }
  __syncthreads();
  int wb = h >> 3, rr = h & 7;
  for (int i = 0; i < 96; ++i) {
    int idx = i * 256 + tid;
    int pos = idx / C_, ch = idx - pos * C_;
    float v = u2f(tile[pos][ch]);
    float y = (v - mean_s[pos]) * rstd_s[pos] * g[ch] + bta[ch];
    int t = ((bb * 64 + wb * 8 + (pos >> 3)) << 6) + (rr << 3) + (pos & 7);
    wins[(size_t)t * C_ + ch] = f2u(y);
  }
}

// ---------------------------------------------------------------------------
// Weight transpose + bf16 cast: in fp32 (K x N) -> out bf16 (N x K).
// LDS-tiled 32x32 so both global read and write are contiguous.
// K, N multiples of 32 for all four weights.
// ---------------------------------------------------------------------------
__global__ __launch_bounds__(256) void transpose_kernel(const float* __restrict__ in,
                                                        u16* __restrict__ out,
                                                        int K, int N) {
  __shared__ u16 t[32][33];
  int k0 = blockIdx.x * 32, n0 = blockIdx.y * 32;
  int tid = threadIdx.x;
  int r = tid >> 3, c4 = (tid & 7) * 4;
  for (int i = 0; i < 4; ++i)
    t[r][c4 + i] = f2u(in[(size_t)(k0 + r) * N + n0 + c4 + i]);
  __syncthreads();
  for (int i = 0; i < 4; ++i)
    out[(size_t)(n0 + r) * K + k0 + c4 + i] = t[c4 + i][r];
}

// ---------------------------------------------------------------------------
// MFMA GEMM (m97 structure): out[M,N] = act(A[M,K] @ Bt[N,K]^T + bias) (+res).
// 128x128 tile / block, 4 waves each 64x64 via 4x4 grid of 16x16x32 bf16 MFMA.
// Staging via global_load_lds width-16 into LINEAR LDS [128][32] (no padding:
// gload_lds dest is wave-uniform base + lane*16 -- m104/m108).
// Verified layouts (m89/m91/m118): A[m=lane&15][k=quad*8+j],
// B[k=quad*8+j][n=lane&15], D col=lane&15, row=quad*4+reg.
// ---------------------------------------------------------------------------
template<int ACT, bool RES, bool OUTF32>
__global__ __launch_bounds__(256) void gemm_kernel(const u16* __restrict__ A,
                                                   const u16* __restrict__ Bt,
                                                   const float* __restrict__ bias,
                                                   const float* __restrict__ res,
                                                   void* __restrict__ out,
                                                   int M, int N, int K) {
  __shared__ __align__(16) u16 As[128][32];
  __shared__ __align__(16) u16 Bs[128][32];
  int tid = threadIdx.x;
  int m0 = blockIdx.x * 128, n0 = blockIdx.y * 128;
  int lane = tid & 63, wv = tid >> 6;
  int rm = (wv >> 1) * 64, rn = (wv & 1) * 64;
  int lr = lane & 15, q = lane >> 4;
  const floatx4 zero = {0.f, 0.f, 0.f, 0.f};
  floatx4 acc[4][4];
  for (int i = 0; i < 4; ++i) for (int j = 0; j < 4; ++j) acc[i][j] = zero;

  // Staging map: 512 chunks of 16B per matrix per K-step. Wave wv, issue s
  // covers chunks [wv*128 + s*64, +64); lane l -> chunk c = that + l.
  // Chunk c -> row r = c>>2, k-part kp = c&3 (8 u16 each).
  int c1 = wv * 128 + lane;             // issue-0 chunk for this thread
  int r1 = c1 >> 2, kp1 = c1 & 3;
  int c2 = c1 + 64;                     // issue-1 chunk
  int r2 = c2 >> 2, kp2 = c2 & 3;
  const u16* gA1 = A  + (size_t)(m0 + r1) * K + kp1 * 8;
  const u16* gA2 = A  + (size_t)(m0 + r2) * K + kp2 * 8;
  const u16* gB1 = Bt + (size_t)(n0 + r1) * K + kp1 * 8;
  const u16* gB2 = Bt + (size_t)(n0 + r2) * K + kp2 * 8;
  u16* lA1 = &As[0][0] + wv * 1024;     // wave-uniform LDS bases (u16 units)
  u16* lA2 = lA1 + 512;
  u16* lB1 = &Bs[0][0] + wv * 1024;
  u16* lB2 = lB1 + 512;

  for (int k0 = 0; k0 < K; k0 += 32) {
    gload_lds16(gA1 + k0, lA1);
    gload_lds16(gA2 + k0, lA2);
    gload_lds16(gB1 + k0, lB1);
    gload_lds16(gB2 + k0, lB2);
    __syncthreads();                    // drains vmcnt -> tile ready
    bf16x8 fa[4], fb[4];
    for (int i = 0; i < 4; ++i) fa[i] = *(const bf16x8*)&As[rm + i * 16 + lr][q * 8];
    for (int j = 0; j < 4; ++j) fb[j] = *(const bf16x8*)&Bs[rn + j * 16 + lr][q * 8];
    for (int i = 0; i < 4; ++i)
      for (int j = 0; j < 4; ++j)
        acc[i][j] = __builtin_amdgcn_mfma_f32_16x16x32_bf16(fa[i], fb[j], acc[i][j], 0, 0, 0);
    __syncthreads();                    // protect LDS before next stage
  }
  for (int i = 0; i < 4; ++i) {
    int mrow = m0 + rm + i * 16 + q * 4;
    for (int j = 0; j < 4; ++j) {
      int ncol = n0 + rn + j * 16 + lr;
      float bv = bias[ncol];
      for (int rr2 = 0; rr2 < 4; ++rr2) {
        float v = acc[i][j][rr2] + bv;
        if (ACT == 1) v = gelu_f(v);
        size_t off = (size_t)(mrow + rr2) * N + ncol;
        if (RES) v += res[off];
        if (OUTF32) ((float*)out)[off] = v;
        else        ((u16*)out)[off] = f2u(v);
      }
    }
  }
}

// ---------------------------------------------------------------------------
// Window attention: one block per (window, head). q,k,v 64x48 in LDS (fp32),
// S = softmax(q k^T * scale) in LDS, O = S v. Register-tiled fp32 vector math.
// ---------------------------------------------------------------------------
__global__ __launch_bounds__(256) void attn_kernel(const u16* __restrict__ qkv,
                                                   u16* __restrict__ attn_out) {
  __shared__ float qs[64][49], ks[64][49], vs[64][49];
  __shared__ float S[64][65];
  __shared__ float inv_l[64];
  int tid = threadIdx.x;
  int win = blockIdx.x >> 3, head = blockIdx.x & 7;
  size_t base = (size_t)win * 64 * N3 + head * HD;
  for (int it = 0; it < 36; ++it) {
    int idx = it * 256 + tid;
    int s = idx / 3072, rem = idx - s * 3072;
    int n = rem / 48, d = rem - n * 48;
    float v = u2f(qkv[base + (size_t)n * N3 + s * C_ + d]);
    if (s == 0) qs[n][d] = v; else if (s == 1) ks[n][d] = v; else vs[n][d] = v;
  }
  __syncthreads();
  {
    int tr = tid >> 4, tc = tid & 15;
    int i0 = tr * 4, j0 = tc * 4;
    float acc[4][4] = {};
    for (int d = 0; d < 48; ++d) {
      float qa[4], kb[4];
      for (int ii = 0; ii < 4; ++ii) qa[ii] = qs[i0 + ii][d];
      for (int jj = 0; jj < 4; ++jj) kb[jj] = ks[j0 + jj][d];
      for (int ii = 0; ii < 4; ++ii)
        for (int jj = 0; jj < 4; ++jj) acc[ii][jj] += qa[ii] * kb[jj];
    }
    const float scale = 0.14433756729740643f;  // 48^-0.5
    for (int ii = 0; ii < 4; ++ii)
      for (int jj = 0; jj < 4; ++jj) S[i0 + ii][j0 + jj] = acc[ii][jj] * scale;
  }
  __syncthreads();
  if (tid < 64) {
    float m = -1e30f;
    for (int j = 0; j < 64; ++j) m = fmaxf(m, S[tid][j]);
    float l = 0.f;
    for (int j = 0; j < 64; ++j) { float e = __expf(S[tid][j] - m); S[tid][j] = e; l += e; }
    inv_l[tid] = 1.0f / l;
  }
  __syncthreads();
  {
    int tr = tid >> 4, tc = tid & 15;
    int i0 = tr * 4, d0 = tc * 3;
    float o[4][3] = {};
    for (int j = 0; j < 64; ++j) {
      float pa[4], vb[3];
      for (int ii = 0; ii < 4; ++ii) pa[ii] = S[i0 + ii][j];
      for (int cc = 0; cc < 3; ++cc) vb[cc] = vs[j][d0 + cc];
      for (int ii = 0; ii < 4; ++ii)
        for (int cc = 0; cc < 3; ++cc) o[ii][cc] += pa[ii] * vb[cc];
    }
    for (int ii = 0; ii < 4; ++ii) {
      float sc = inv_l[i0 + ii];
      for (int cc = 0; cc < 3; ++cc)
        attn_out[(size_t)(win * 64 + i0 + ii) * C_ + head * HD + d0 + cc] = f2u(o[ii][cc] * sc);
    }
  }
}

// ---------------------------------------------------------------------------
// LayerNorm2 (token layout, fp32 input from xc): one wave per row, 4 rows/block.
// ---------------------------------------------------------------------------
__global__ __launch_bounds__(256) void ln2_kernel(const float* __restrict__ xc,
                                                  const float* __restrict__ g,
                                                  const float* __restrict__ bta,
                                                  u16* __restrict__ out) {
  int tid = threadIdx.x;
  int row = blockIdx.x * 4 + (tid >> 6);
  int lane = tid & 63;
  const float* xr = xc + (size_t)row * C_;
  float v[6];
  float sm = 0.f, sq = 0.f;
  for (int i = 0; i < 6; ++i) {
    v[i] = xr[i * 64 + lane];
    sm += v[i]; sq += v[i] * v[i];
  }
  for (int off = 32; off > 0; off >>= 1) { sm += __shfl_down(sm, off, 64); sq += __shfl_down(sq, off, 64); }
  sm = __shfl(sm, 0, 64); sq = __shfl(sq, 0, 64);
  float m = sm / (float)C_;
  float rstd = rsqrtf(sq / (float)C_ - m * m + 1e-5f);
  u16* orow = out + (size_t)row * C_;
  for (int i = 0; i < 6; ++i) {
    int ch = i * 64 + lane;
    orow[ch] = f2u((v[i] - m) * rstd * g[ch] + bta[ch]);
  }
}

// ---------------------------------------------------------------------------
// Final (per chunk): token layout fp32 -> (C,H,W) fp32 with window reverse +
// roll(+4,+4). Two passes of 192 channels (fp32 LDS tile fits 64 KB).
// Diagnostic sentinels: NaN -> 777, Inf -> 888.
// ---------------------------------------------------------------------------
__global__ __launch_bounds__(256) void permute_kernel(const float* __restrict__ fin,
                                                      float* __restrict__ out) {
  __shared__ float tile[64][194];
  int tid = threadIdx.x;
  int bb = blockIdx.x >> 6, h = blockIdx.x & 63;   // local batch, rolled row
  int h0 = (h + 4) & 63;
  int wb = h >> 3, rr = h & 7;
  for (int half = 0; half < 2; ++half) {
    int c0 = half * 192;
    __syncthreads();
    for (int i = 0; i < 48; ++i) {
      int idx = i * 256 + tid;            // 0..12287
      int w = idx / 192, cl = idx - w * 192;
      int t = ((bb * 64 + wb * 8 + (w >> 3)) << 6) + (rr << 3) + (w & 7);
      tile[w][cl] = fin[(size_t)t * C_ + c0 + cl];
    }
    __syncthreads();
    for (int i = 0; i < 48; ++i) {
      int idx = i * 256 + tid;
      int cl = idx / 64, w = idx & 63;    // cl 0..191
      int w0 = (w + 4) & 63;
      float v = tile[w][cl];
      if (isnan(v)) v = 777.0f;           // NaN sentinel
      else if (isinf(v)) v = 888.0f;      // Inf sentinel
      size_t o = ((size_t)(bb * C_ + c0 + cl) << 12) + (h0 << 6) + w0;
      out[o] = v;
    }
  }
}

// ---------------------------------------------------------------------------
// fp32 inputs, fp32 output. Chunked by batch (2 batches / chunk).
// Workspace: 3.4 MB weights + 6.3 (W1 bf16) + 25.2 (W2 bf16) + 6.3 (W3 bf16)
//            + 12.6 (W4 fp32) = ~51.4 MiB.
// d_out (fp32) doubles as xc scratch: chunk's token range == NCHW flat range.
// ---------------------------------------------------------------------------
extern "C" void kernel_launch(void* const* d_in, const int* in_sizes, int n_in,
                              void* d_out, int out_size, void* d_ws, size_t ws_size,
                              hipStream_t stream) {
  const float* x      = (const float*)d_in[0];
  const float* n1g    = (const float*)d_in[1];
  const float* n1b    = (const float*)d_in[2];
  const float* qkv_w  = (const float*)d_in[3];
  const float* qkv_b  = (const float*)d_in[4];
  const float* proj_w = (const float*)d_in[5];
  const float* proj_b = (const float*)d_in[6];
  const float* n2g    = (const float*)d_in[7];
  const float* n2b    = (const float*)d_in[8];
  const float* w1     = (const float*)d_in[9];
  const float* b1     = (const float*)d_in[10];
  const float* w2     = (const float*)d_in[11];
  const float* b2     = (const float*)d_in[12];
  float* outp = (float*)d_out;

  char* ws = (char*)d_ws;
  size_t off = 0;
  u16* wT_qkv  = (u16*)(ws + off); off += (size_t)N3   * C_   * 2;
  u16* wT_proj = (u16*)(ws + off); off += (size_t)C_   * C_   * 2;
  u16* wT_w1   = (u16*)(ws + off); off += (size_t)CHID * C_   * 2;
  u16* wT_w2   = (u16*)(ws + off); off += (size_t)C_   * CHID * 2;
  u16*   W1 = (u16*)(ws + off);   off += (size_t)CTOK * C_   * 2;  // wins / ln2out
  u16*   W2 = (u16*)(ws + off);   off += (size_t)CTOK * CHID * 2;  // qkv / hidden
  u16*   W3 = (u16*)(ws + off);   off += (size_t)CTOK * C_   * 2;  // attn_out
  float* W4 = (float*)(ws + off); off += (size_t)CTOK * C_   * 4;  // mlp2out+res

  transpose_kernel<<<dim3(C_ / 32, N3 / 32), 256, 0, stream>>>(qkv_w, wT_qkv, C_, N3);
  transpose_kernel<<<dim3(C_ / 32, C_ / 32), 256, 0, stream>>>(proj_w, wT_proj, C_, C_);
  transpose_kernel<<<dim3(C_ / 32, CHID / 32), 256, 0, stream>>>(w1, wT_w1, C_, CHID);
  transpose_kernel<<<dim3(CHID / 32, C_ / 32), 256, 0, stream>>>(w2, wT_w2, CHID, C_);

  for (int c = 0; c < NCHUNK; ++c) {
    size_t xelem = (size_t)c * BPC * C_ * H_ * W_;  // chunk's NCHW elem offset
    size_t toff  = (size_t)c * CTOK * C_;           // chunk's token elem offset (== xelem)

    // 1. roll + window partition + LN1: fp32 x -> bf16 wins
    ln1_kernel<<<BPC * H_, 256, 0, stream>>>(x + xelem, n1g, n1b, W1);
    // 2. qkv GEMM (bf16 out)
    gemm_kernel<0, false, false><<<dim3(CTOK / 128, N3 / 128), 256, 0, stream>>>(
        W1, wT_qkv, qkv_b, nullptr, W2, CTOK, N3, C_);
    // 3. attention (bf16 out)
    attn_kernel<<<CWIN * 8, 256, 0, stream>>>(W2, W3);
    // 4. proj -> xc fp32 (in d_out)
    gemm_kernel<0, false, true><<<dim3(CTOK / 128, C_ / 128), 256, 0, stream>>>(
        W3, wT_proj, proj_b, nullptr, outp + toff, CTOK, C_, C_);
    // 5. LN2 (fp32 in, bf16 out)
    ln2_kernel<<<CTOK / 4, 256, 0, stream>>>(outp + toff, n2g, n2b, W1);
    // 6. MLP1 + gelu (bf16 out)
    gemm_kernel<1, false, false><<<dim3(CTOK / 128, CHID / 128), 256, 0, stream>>>(
        W1, wT_w1, b1, nullptr, W2, CTOK, CHID, C_);
    // 7. MLP2 + residual(xc fp32) -> fp32
    gemm_kernel<0, true, true><<<dim3(CTOK / 128, C_ / 128), 256, 0, stream>>>(
        W2, wT_w2, b2, outp + toff, W4, CTOK, C_, CHID);
    // 8. window reverse + roll back -> final fp32 output for this chunk
    permute_kernel<<<BPC * H_, 256, 0, stream>>>(W4, outp + xelem);
  }
}

// Round 7
// 1048.460 us; speedup vs baseline: 1.4385x; 1.4385x over previous
//
#include <hip/hip_runtime.h>
#include <hip/hip_bf16.h>

typedef unsigned short u16;
typedef __bf16 bf16x8 __attribute__((ext_vector_type(8)));
typedef float  floatx4 __attribute__((ext_vector_type(4)));
typedef u16    u16x8   __attribute__((ext_vector_type(8)));

#define B_    16
#define C_    384
#define H_    64
#define W_    64
#define TOK   65536      // B*H*W tokens
#define N3    1152       // 3*C
#define CHID  1536       // 4*C
#define HD    48         // head dim

__device__ __forceinline__ float u2f(u16 u) { return __uint_as_float(((unsigned)u) << 16); }
__device__ __forceinline__ u16   f2u(float f) { __bf16 b = (__bf16)f; return *reinterpret_cast<u16*>(&b); }
__device__ __forceinline__ float gelu_f(float v) { return 0.5f * v * (1.0f + erff(v * 0.70710678118654752f)); }

// Async global->LDS, 16B per lane. LDS dest is wave-uniform base + lane*16
// (m104/m108); global src is per-lane.
__device__ __forceinline__ void gload_lds16(const u16* g, u16* l) {
  __builtin_amdgcn_global_load_lds(
      (const __attribute__((address_space(1))) void*)g,
      (__attribute__((address_space(3))) void*)l,
      16, 0, 0);
}

// ---------------------------------------------------------------------------
// roll(-4,-4) + window partition + LayerNorm1 (fp32 input).
// Token layout: t = (b_local*64 + (h/8)*8 + (w/8))*64 + (h%8)*8 + (w%8),
// h/w in rolled coords; rolled (h,w) reads original ((h+4)%64,(w+4)%64).
// grid = bpc*64; blockIdx>>6 = local batch, &63 = rolled row.
// ---------------------------------------------------------------------------
__global__ __launch_bounds__(256) void ln1_kernel(const float* __restrict__ x,
                                                  const float* __restrict__ g,
                                                  const float* __restrict__ bta,
                                                  u16* __restrict__ wins) {
  __shared__ u16 tile[64][C_ + 2];
  __shared__ float psum[4][64], psq[4][64], mean_s[64], rstd_s[64];
  int tid = threadIdx.x;
  int bb = blockIdx.x >> 6;        // local batch
  int h  = blockIdx.x & 63;        // rolled row
  int h0 = (h + 4) & 63;           // original row
  for (int i = 0; i < 96; ++i) {
    int idx = i * 256 + tid;
    int ch = idx >> 6, wr = idx & 63;
    int w0 = (wr + 4) & 63;
    size_t xi = ((size_t)(bb * C_ + ch) << 12) + (h0 << 6) + w0;
    tile[wr][ch] = f2u(x[xi]);
  }
  __syncthreads();
  {
    int s = tid >> 6, p = tid & 63;
    float sm = 0.f, sq = 0.f;
    for (int ii = 0; ii < 96; ++ii) {
      float v = u2f(tile[p][s * 96 + ii]);
      sm += v; sq += v * v;
    }
    psum[s][p] = sm; psq[s][p] = sq;
  }
  __syncthreads();
  if (tid < 64) {
    float m  = psum[0][tid] + psum[1][tid] + psum[2][tid] + psum[3][tid];
    float q2 = psq[0][tid] + psq[1][tid] + psq[2][tid] + psq[3][tid];
    m /= (float)C_;
    float var = q2 / (float)C_ - m * m;
    mean_s[tid] = m;
    rstd_s[tid] = rsqrtf(var + 1e-5f);
  }
  __syncthreads();
  int wb = h >> 3, rr = h & 7;
  for (int i = 0; i < 96; ++i) {
    int idx = i * 256 + tid;
    int pos = idx / C_, ch = idx - pos * C_;
    float v = u2f(tile[pos][ch]);
    float y = (v - mean_s[pos]) * rstd_s[pos] * g[ch] + bta[ch];
    int t = ((bb * 64 + wb * 8 + (pos >> 3)) << 6) + (rr << 3) + (pos & 7);
    wins[(size_t)t * C_ + ch] = f2u(y);
  }
}

// ---------------------------------------------------------------------------
// Weight transpose + bf16 cast: in fp32 (K x N) -> out bf16 (N x K).
// LDS-tiled 32x32 so both global read and write are contiguous.
// ---------------------------------------------------------------------------
__global__ __launch_bounds__(256) void transpose_kernel(const float* __restrict__ in,
                                                        u16* __restrict__ out,
                                                        int K, int N) {
  __shared__ u16 t[32][33];
  int k0 = blockIdx.x * 32, n0 = blockIdx.y * 32;
  int tid = threadIdx.x;
  int r = tid >> 3, c4 = (tid & 7) * 4;
  for (int i = 0; i < 4; ++i)
    t[r][c4 + i] = f2u(in[(size_t)(k0 + r) * N + n0 + c4 + i]);
  __syncthreads();
  for (int i = 0; i < 4; ++i)
    out[(size_t)(n0 + r) * K + k0 + c4 + i] = t[c4 + i][r];
}

// ---------------------------------------------------------------------------
// MFMA GEMM (m97 structure): out[M,N] = act(A[M,K] @ Bt[N,K]^T + bias) (+res).
// 128x128 tile / block, 4 waves each 64x64 via 4x4 grid of 16x16x32 bf16 MFMA.
// Staging via global_load_lds width-16 into LINEAR LDS [128][32] (no padding:
// gload_lds dest is wave-uniform base + lane*16 -- m104/m108).
// Verified layouts (m89/m91/m118): A[m=lane&15][k=quad*8+j],
// B[k=quad*8+j][n=lane&15], D col=lane&15, row=quad*4+reg.
// ---------------------------------------------------------------------------
template<int ACT, bool RES, bool OUTF32>
__global__ __launch_bounds__(256) void gemm_kernel(const u16* __restrict__ A,
                                                   const u16* __restrict__ Bt,
                                                   const float* __restrict__ bias,
                                                   const float* __restrict__ res,
                                                   void* __restrict__ out,
                                                   int M, int N, int K) {
  __shared__ __align__(16) u16 As[128][32];
  __shared__ __align__(16) u16 Bs[128][32];
  int tid = threadIdx.x;
  int m0 = blockIdx.x * 128, n0 = blockIdx.y * 128;
  int lane = tid & 63, wv = tid >> 6;
  int rm = (wv >> 1) * 64, rn = (wv & 1) * 64;
  int lr = lane & 15, q = lane >> 4;
  const floatx4 zero = {0.f, 0.f, 0.f, 0.f};
  floatx4 acc[4][4];
  for (int i = 0; i < 4; ++i) for (int j = 0; j < 4; ++j) acc[i][j] = zero;

  // Staging map: 512 chunks of 16B per matrix per K-step. Wave wv, issue s
  // covers chunks [wv*128 + s*64, +64); lane l -> chunk c = that + l.
  // Chunk c -> row r = c>>2, k-part kp = c&3 (8 u16 each).
  int c1 = wv * 128 + lane;             // issue-0 chunk for this thread
  int r1 = c1 >> 2, kp1 = c1 & 3;
  int c2 = c1 + 64;                     // issue-1 chunk
  int r2 = c2 >> 2, kp2 = c2 & 3;
  const u16* gA1 = A  + (size_t)(m0 + r1) * K + kp1 * 8;
  const u16* gA2 = A  + (size_t)(m0 + r2) * K + kp2 * 8;
  const u16* gB1 = Bt + (size_t)(n0 + r1) * K + kp1 * 8;
  const u16* gB2 = Bt + (size_t)(n0 + r2) * K + kp2 * 8;
  u16* lA1 = &As[0][0] + wv * 1024;     // wave-uniform LDS bases (u16 units)
  u16* lA2 = lA1 + 512;
  u16* lB1 = &Bs[0][0] + wv * 1024;
  u16* lB2 = lB1 + 512;

  for (int k0 = 0; k0 < K; k0 += 32) {
    gload_lds16(gA1 + k0, lA1);
    gload_lds16(gA2 + k0, lA2);
    gload_lds16(gB1 + k0, lB1);
    gload_lds16(gB2 + k0, lB2);
    __syncthreads();                    // drains vmcnt -> tile ready
    bf16x8 fa[4], fb[4];
    for (int i = 0; i < 4; ++i) fa[i] = *(const bf16x8*)&As[rm + i * 16 + lr][q * 8];
    for (int j = 0; j < 4; ++j) fb[j] = *(const bf16x8*)&Bs[rn + j * 16 + lr][q * 8];
    for (int i = 0; i < 4; ++i)
      for (int j = 0; j < 4; ++j)
        acc[i][j] = __builtin_amdgcn_mfma_f32_16x16x32_bf16(fa[i], fb[j], acc[i][j], 0, 0, 0);
    __syncthreads();                    // protect LDS before next stage
  }
  for (int i = 0; i < 4; ++i) {
    int mrow = m0 + rm + i * 16 + q * 4;
    for (int j = 0; j < 4; ++j) {
      int ncol = n0 + rn + j * 16 + lr;
      float bv = bias[ncol];
      for (int rr2 = 0; rr2 < 4; ++rr2) {
        float v = acc[i][j][rr2] + bv;
        if (ACT == 1) v = gelu_f(v);
        size_t off = (size_t)(mrow + rr2) * N + ncol;
        if (RES) v += res[off];
        if (OUTF32) ((float*)out)[off] = v;
        else        ((u16*)out)[off] = f2u(v);
      }
    }
  }
}

// ---------------------------------------------------------------------------
// Window attention: one block per (window, head). q,k,v 64x48 in LDS (fp32),
// S = softmax(q k^T * scale) in LDS, O = S v. Register-tiled fp32 vector math.
// ---------------------------------------------------------------------------
__global__ __launch_bounds__(256) void attn_kernel(const u16* __restrict__ qkv,
                                                   u16* __restrict__ attn_out) {
  __shared__ float qs[64][49], ks[64][49], vs[64][49];
  __shared__ float S[64][65];
  __shared__ float inv_l[64];
  int tid = threadIdx.x;
  int win = blockIdx.x >> 3, head = blockIdx.x & 7;
  size_t base = (size_t)win * 64 * N3 + head * HD;
  for (int it = 0; it < 36; ++it) {
    int idx = it * 256 + tid;
    int s = idx / 3072, rem = idx - s * 3072;
    int n = rem / 48, d = rem - n * 48;
    float v = u2f(qkv[base + (size_t)n * N3 + s * C_ + d]);
    if (s == 0) qs[n][d] = v; else if (s == 1) ks[n][d] = v; else vs[n][d] = v;
  }
  __syncthreads();
  {
    int tr = tid >> 4, tc = tid & 15;
    int i0 = tr * 4, j0 = tc * 4;
    float acc[4][4] = {};
    for (int d = 0; d < 48; ++d) {
      float qa[4], kb[4];
      for (int ii = 0; ii < 4; ++ii) qa[ii] = qs[i0 + ii][d];
      for (int jj = 0; jj < 4; ++jj) kb[jj] = ks[j0 + jj][d];
      for (int ii = 0; ii < 4; ++ii)
        for (int jj = 0; jj < 4; ++jj) acc[ii][jj] += qa[ii] * kb[jj];
    }
    const float scale = 0.14433756729740643f;  // 48^-0.5
    for (int ii = 0; ii < 4; ++ii)
      for (int jj = 0; jj < 4; ++jj) S[i0 + ii][j0 + jj] = acc[ii][jj] * scale;
  }
  __syncthreads();
  if (tid < 64) {
    float m = -1e30f;
    for (int j = 0; j < 64; ++j) m = fmaxf(m, S[tid][j]);
    float l = 0.f;
    for (int j = 0; j < 64; ++j) { float e = __expf(S[tid][j] - m); S[tid][j] = e; l += e; }
    inv_l[tid] = 1.0f / l;
  }
  __syncthreads();
  {
    int tr = tid >> 4, tc = tid & 15;
    int i0 = tr * 4, d0 = tc * 3;
    float o[4][3] = {};
    for (int j = 0; j < 64; ++j) {
      float pa[4], vb[3];
      for (int ii = 0; ii < 4; ++ii) pa[ii] = S[i0 + ii][j];
      for (int cc = 0; cc < 3; ++cc) vb[cc] = vs[j][d0 + cc];
      for (int ii = 0; ii < 4; ++ii)
        for (int cc = 0; cc < 3; ++cc) o[ii][cc] += pa[ii] * vb[cc];
    }
    for (int ii = 0; ii < 4; ++ii) {
      float sc = inv_l[i0 + ii];
      for (int cc = 0; cc < 3; ++cc)
        attn_out[(size_t)(win * 64 + i0 + ii) * C_ + head * HD + d0 + cc] = f2u(o[ii][cc] * sc);
    }
  }
}

// ---------------------------------------------------------------------------
// LayerNorm2 (token layout, fp32 input from xc): one wave per row, 4 rows/block.
// ---------------------------------------------------------------------------
__global__ __launch_bounds__(256) void ln2_kernel(const float* __restrict__ xc,
                                                  const float* __restrict__ g,
                                                  const float* __restrict__ bta,
                                                  u16* __restrict__ out) {
  int tid = threadIdx.x;
  int row = blockIdx.x * 4 + (tid >> 6);
  int lane = tid & 63;
  const float* xr = xc + (size_t)row * C_;
  float v[6];
  float sm = 0.f, sq = 0.f;
  for (int i = 0; i < 6; ++i) {
    v[i] = xr[i * 64 + lane];
    sm += v[i]; sq += v[i] * v[i];
  }
  for (int off = 32; off > 0; off >>= 1) { sm += __shfl_down(sm, off, 64); sq += __shfl_down(sq, off, 64); }
  sm = __shfl(sm, 0, 64); sq = __shfl(sq, 0, 64);
  float m = sm / (float)C_;
  float rstd = rsqrtf(sq / (float)C_ - m * m + 1e-5f);
  u16* orow = out + (size_t)row * C_;
  for (int i = 0; i < 6; ++i) {
    int ch = i * 64 + lane;
    orow[ch] = f2u((v[i] - m) * rstd * g[ch] + bta[ch]);
  }
}

// ---------------------------------------------------------------------------
// Final (per chunk): token layout fp32 -> (C,H,W) fp32 with window reverse +
// roll(+4,+4). Two passes of 192 channels (fp32 LDS tile fits 64 KB).
// Diagnostic sentinels: NaN -> 777, Inf -> 888.
// ---------------------------------------------------------------------------
__global__ __launch_bounds__(256) void permute_kernel(const float* __restrict__ fin,
                                                      float* __restrict__ out) {
  __shared__ float tile[64][194];
  int tid = threadIdx.x;
  int bb = blockIdx.x >> 6, h = blockIdx.x & 63;   // local batch, rolled row
  int h0 = (h + 4) & 63;
  int wb = h >> 3, rr = h & 7;
  for (int half = 0; half < 2; ++half) {
    int c0 = half * 192;
    __syncthreads();
    for (int i = 0; i < 48; ++i) {
      int idx = i * 256 + tid;            // 0..12287
      int w = idx / 192, cl = idx - w * 192;
      int t = ((bb * 64 + wb * 8 + (w >> 3)) << 6) + (rr << 3) + (w & 7);
      tile[w][cl] = fin[(size_t)t * C_ + c0 + cl];
    }
    __syncthreads();
    for (int i = 0; i < 48; ++i) {
      int idx = i * 256 + tid;
      int cl = idx / 64, w = idx & 63;    // cl 0..191
      int w0 = (w + 4) & 63;
      float v = tile[w][cl];
      if (isnan(v)) v = 777.0f;           // NaN sentinel
      else if (isinf(v)) v = 888.0f;      // Inf sentinel
      size_t o = ((size_t)(bb * C_ + c0 + cl) << 12) + (h0 << 6) + w0;
      out[o] = v;
    }
  }
}

// ---------------------------------------------------------------------------
// fp32 inputs, fp32 output. Chunked by batch; chunk count auto-selected at
// runtime: smallest NCHUNK in {2,4,8} whose workspace footprint fits ws_size.
// Footprint = 3.4 MB weights + ctok*6144 B (W1 bf16 + W2 bf16 + W3 bf16 +
// W4 fp32). NCHUNK=2 -> ~205 MB (expected pick given observed 384 MiB pool).
// d_out (fp32) doubles as xc scratch: chunk's token range == NCHW flat range.
// ---------------------------------------------------------------------------
extern "C" void kernel_launch(void* const* d_in, const int* in_sizes, int n_in,
                              void* d_out, int out_size, void* d_ws, size_t ws_size,
                              hipStream_t stream) {
  const float* x      = (const float*)d_in[0];
  const float* n1g    = (const float*)d_in[1];
  const float* n1b    = (const float*)d_in[2];
  const float* qkv_w  = (const float*)d_in[3];
  const float* qkv_b  = (const float*)d_in[4];
  const float* proj_w = (const float*)d_in[5];
  const float* proj_b = (const float*)d_in[6];
  const float* n2g    = (const float*)d_in[7];
  const float* n2b    = (const float*)d_in[8];
  const float* w1     = (const float*)d_in[9];
  const float* b1     = (const float*)d_in[10];
  const float* w2     = (const float*)d_in[11];
  const float* b2     = (const float*)d_in[12];
  float* outp = (float*)d_out;

  const size_t wbytes = ((size_t)N3 * C_ + (size_t)C_ * C_ +
                         (size_t)CHID * C_ + (size_t)C_ * CHID) * 2;  // 3.46 MB
  int nchunk = 8;
  for (int cand = 2; cand <= 8; cand *= 2) {
    size_t need = wbytes + (size_t)(TOK / cand) * 6144;
    if (need <= ws_size) { nchunk = cand; break; }
  }
  const int bpc  = B_ / nchunk;       // batches per chunk
  const int ctok = TOK / nchunk;      // tokens per chunk
  const int cwin = ctok / 64;         // windows per chunk

  char* ws = (char*)d_ws;
  size_t off = 0;
  u16* wT_qkv  = (u16*)(ws + off); off += (size_t)N3   * C_   * 2;
  u16* wT_proj = (u16*)(ws + off); off += (size_t)C_   * C_   * 2;
  u16* wT_w1   = (u16*)(ws + off); off += (size_t)CHID * C_   * 2;
  u16* wT_w2   = (u16*)(ws + off); off += (size_t)C_   * CHID * 2;
  u16*   W1 = (u16*)(ws + off);   off += (size_t)ctok * C_   * 2;  // wins / ln2out
  u16*   W2 = (u16*)(ws + off);   off += (size_t)ctok * CHID * 2;  // qkv / hidden
  u16*   W3 = (u16*)(ws + off);   off += (size_t)ctok * C_   * 2;  // attn_out
  float* W4 = (float*)(ws + off); off += (size_t)ctok * C_   * 4;  // mlp2out+res

  transpose_kernel<<<dim3(C_ / 32, N3 / 32), 256, 0, stream>>>(qkv_w, wT_qkv, C_, N3);
  transpose_kernel<<<dim3(C_ / 32, C_ / 32), 256, 0, stream>>>(proj_w, wT_proj, C_, C_);
  transpose_kernel<<<dim3(C_ / 32, CHID / 32), 256, 0, stream>>>(w1, wT_w1, C_, CHID);
  transpose_kernel<<<dim3(CHID / 32, C_ / 32), 256, 0, stream>>>(w2, wT_w2, CHID, C_);

  for (int c = 0; c < nchunk; ++c) {
    size_t xelem = (size_t)c * bpc * C_ * H_ * W_;  // chunk's NCHW elem offset
    size_t toff  = (size_t)c * ctok * C_;           // chunk's token elem offset (== xelem)

    // 1. roll + window partition + LN1: fp32 x -> bf16 wins
    ln1_kernel<<<bpc * H_, 256, 0, stream>>>(x + xelem, n1g, n1b, W1);
    // 2. qkv GEMM (bf16 out)
    gemm_kernel<0, false, false><<<dim3(ctok / 128, N3 / 128), 256, 0, stream>>>(
        W1, wT_qkv, qkv_b, nullptr, W2, ctok, N3, C_);
    // 3. attention (bf16 out)
    attn_kernel<<<cwin * 8, 256, 0, stream>>>(W2, W3);
    // 4. proj -> xc fp32 (in d_out)
    gemm_kernel<0, false, true><<<dim3(ctok / 128, C_ / 128), 256, 0, stream>>>(
        W3, wT_proj, proj_b, nullptr, outp + toff, ctok, C_, C_);
    // 5. LN2 (fp32 in, bf16 out)
    ln2_kernel<<<ctok / 4, 256, 0, stream>>>(outp + toff, n2g, n2b, W1);
    // 6. MLP1 + gelu (bf16 out)
    gemm_kernel<1, false, false><<<dim3(ctok / 128, CHID / 128), 256, 0, stream>>>(
        W1, wT_w1, b1, nullptr, W2, ctok, CHID, C_);
    // 7. MLP2 + residual(xc fp32) -> fp32
    gemm_kernel<0, true, true><<<dim3(ctok / 128, C_ / 128), 256, 0, stream>>>(
        W2, wT_w2, b2, outp + toff, W4, ctok, C_, CHID);
    // 8. window reverse + roll back -> final fp32 output for this chunk
    permute_kernel<<<bpc * H_, 256, 0, stream>>>(W4, outp + xelem);
  }
}

// Round 8
// 889.473 us; speedup vs baseline: 1.6956x; 1.1787x over previous
//
#include <hip/hip_runtime.h>
#include <hip/hip_bf16.h>

typedef unsigned short u16;
typedef __bf16 bf16x8 __attribute__((ext_vector_type(8)));
typedef float  floatx4 __attribute__((ext_vector_type(4)));
typedef u16    u16x8   __attribute__((ext_vector_type(8)));

#define B_    16
#define C_    384
#define H_    64
#define W_    64
#define TOK   65536      // B*H*W tokens
#define N3    1152       // 3*C
#define CHID  1536       // 4*C
#define HD    48         // head dim

__device__ __forceinline__ float u2f(u16 u) { return __uint_as_float(((unsigned)u) << 16); }
__device__ __forceinline__ u16   f2u(float f) { __bf16 b = (__bf16)f; return *reinterpret_cast<u16*>(&b); }
__device__ __forceinline__ float gelu_f(float v) { return 0.5f * v * (1.0f + erff(v * 0.70710678118654752f)); }

// Async global->LDS, 16B per lane. LDS dest is wave-uniform base + lane*16
// (m104/m108); global src is per-lane.
__device__ __forceinline__ void gload_lds16(const u16* g, u16* l) {
  __builtin_amdgcn_global_load_lds(
      (const __attribute__((address_space(1))) void*)g,
      (__attribute__((address_space(3))) void*)l,
      16, 0, 0);
}

// ---------------------------------------------------------------------------
// roll(-4,-4) + window partition + LayerNorm1 (fp32 input).
// Token layout: t = (b_local*64 + (h/8)*8 + (w/8))*64 + (h%8)*8 + (w%8),
// h/w in rolled coords; rolled (h,w) reads original ((h+4)%64,(w+4)%64).
// grid = bpc*64; blockIdx>>6 = local batch, &63 = rolled row.
// ---------------------------------------------------------------------------
__global__ __launch_bounds__(256) void ln1_kernel(const float* __restrict__ x,
                                                  const float* __restrict__ g,
                                                  const float* __restrict__ bta,
                                                  u16* __restrict__ wins) {
  __shared__ u16 tile[64][C_ + 2];
  __shared__ float psum[4][64], psq[4][64], mean_s[64], rstd_s[64];
  int tid = threadIdx.x;
  int bb = blockIdx.x >> 6;        // local batch
  int h  = blockIdx.x & 63;        // rolled row
  int h0 = (h + 4) & 63;           // original row
  for (int i = 0; i < 96; ++i) {
    int idx = i * 256 + tid;
    int ch = idx >> 6, wr = idx & 63;
    int w0 = (wr + 4) & 63;
    size_t xi = ((size_t)(bb * C_ + ch) << 12) + (h0 << 6) + w0;
    tile[wr][ch] = f2u(x[xi]);
  }
  __syncthreads();
  {
    int s = tid >> 6, p = tid & 63;
    float sm = 0.f, sq = 0.f;
    for (int ii = 0; ii < 96; ++ii) {
      float v = u2f(tile[p][s * 96 + ii]);
      sm += v; sq += v * v;
    }
    psum[s][p] = sm; psq[s][p] = sq;
  }
  __syncthreads();
  if (tid < 64) {
    float m  = psum[0][tid] + psum[1][tid] + psum[2][tid] + psum[3][tid];
    float q2 = psq[0][tid] + psq[1][tid] + psq[2][tid] + psq[3][tid];
    m /= (float)C_;
    float var = q2 / (float)C_ - m * m;
    mean_s[tid] = m;
    rstd_s[tid] = rsqrtf(var + 1e-5f);
  }
  __syncthreads();
  int wb = h >> 3, rr = h & 7;
  for (int i = 0; i < 96; ++i) {
    int idx = i * 256 + tid;
    int pos = idx / C_, ch = idx - pos * C_;
    float v = u2f(tile[pos][ch]);
    float y = (v - mean_s[pos]) * rstd_s[pos] * g[ch] + bta[ch];
    int t = ((bb * 64 + wb * 8 + (pos >> 3)) << 6) + (rr << 3) + (pos & 7);
    wins[(size_t)t * C_ + ch] = f2u(y);
  }
}

// ---------------------------------------------------------------------------
// Weight transpose + bf16 cast: in fp32 (K x N) -> out bf16 (N x K).
// LDS-tiled 32x32 so both global read and write are contiguous.
// ---------------------------------------------------------------------------
__global__ __launch_bounds__(256) void transpose_kernel(const float* __restrict__ in,
                                                        u16* __restrict__ out,
                                                        int K, int N) {
  __shared__ u16 t[32][33];
  int k0 = blockIdx.x * 32, n0 = blockIdx.y * 32;
  int tid = threadIdx.x;
  int r = tid >> 3, c4 = (tid & 7) * 4;
  for (int i = 0; i < 4; ++i)
    t[r][c4 + i] = f2u(in[(size_t)(k0 + r) * N + n0 + c4 + i]);
  __syncthreads();
  for (int i = 0; i < 4; ++i)
    out[(size_t)(n0 + r) * K + k0 + c4 + i] = t[c4 + i][r];
}

// ---------------------------------------------------------------------------
// MFMA GEMM (m97 structure): out[M,N] = act(A[M,K] @ Bt[N,K]^T + bias) (+res).
// 128x128 tile / block, 4 waves each 64x64 via 4x4 grid of 16x16x32 bf16 MFMA.
// Staging via global_load_lds width-16 into LINEAR LDS [128][32] (no padding:
// gload_lds dest is wave-uniform base + lane*16 -- m104/m108).
// Verified layouts (m89/m91/m118): A[m=lane&15][k=quad*8+j],
// B[k=quad*8+j][n=lane&15], D col=lane&15, row=quad*4+reg.
// ---------------------------------------------------------------------------
template<int ACT, bool RES, bool OUTF32>
__global__ __launch_bounds__(256) void gemm_kernel(const u16* __restrict__ A,
                                                   const u16* __restrict__ Bt,
                                                   const float* __restrict__ bias,
                                                   const float* __restrict__ res,
                                                   void* __restrict__ out,
                                                   int M, int N, int K) {
  __shared__ __align__(16) u16 As[128][32];
  __shared__ __align__(16) u16 Bs[128][32];
  int tid = threadIdx.x;
  int m0 = blockIdx.x * 128, n0 = blockIdx.y * 128;
  int lane = tid & 63, wv = tid >> 6;
  int rm = (wv >> 1) * 64, rn = (wv & 1) * 64;
  int lr = lane & 15, q = lane >> 4;
  const floatx4 zero = {0.f, 0.f, 0.f, 0.f};
  floatx4 acc[4][4];
  for (int i = 0; i < 4; ++i) for (int j = 0; j < 4; ++j) acc[i][j] = zero;

  // Staging map: 512 chunks of 16B per matrix per K-step. Wave wv, issue s
  // covers chunks [wv*128 + s*64, +64); lane l -> chunk c = that + l.
  // Chunk c -> row r = c>>2, k-part kp = c&3 (8 u16 each).
  int c1 = wv * 128 + lane;             // issue-0 chunk for this thread
  int r1 = c1 >> 2, kp1 = c1 & 3;
  int c2 = c1 + 64;                     // issue-1 chunk
  int r2 = c2 >> 2, kp2 = c2 & 3;
  const u16* gA1 = A  + (size_t)(m0 + r1) * K + kp1 * 8;
  const u16* gA2 = A  + (size_t)(m0 + r2) * K + kp2 * 8;
  const u16* gB1 = Bt + (size_t)(n0 + r1) * K + kp1 * 8;
  const u16* gB2 = Bt + (size_t)(n0 + r2) * K + kp2 * 8;
  u16* lA1 = &As[0][0] + wv * 1024;     // wave-uniform LDS bases (u16 units)
  u16* lA2 = lA1 + 512;
  u16* lB1 = &Bs[0][0] + wv * 1024;
  u16* lB2 = lB1 + 512;

  for (int k0 = 0; k0 < K; k0 += 32) {
    gload_lds16(gA1 + k0, lA1);
    gload_lds16(gA2 + k0, lA2);
    gload_lds16(gB1 + k0, lB1);
    gload_lds16(gB2 + k0, lB2);
    __syncthreads();                    // drains vmcnt -> tile ready
    bf16x8 fa[4], fb[4];
    for (int i = 0; i < 4; ++i) fa[i] = *(const bf16x8*)&As[rm + i * 16 + lr][q * 8];
    for (int j = 0; j < 4; ++j) fb[j] = *(const bf16x8*)&Bs[rn + j * 16 + lr][q * 8];
    for (int i = 0; i < 4; ++i)
      for (int j = 0; j < 4; ++j)
        acc[i][j] = __builtin_amdgcn_mfma_f32_16x16x32_bf16(fa[i], fb[j], acc[i][j], 0, 0, 0);
    __syncthreads();                    // protect LDS before next stage
  }
  for (int i = 0; i < 4; ++i) {
    int mrow = m0 + rm + i * 16 + q * 4;
    for (int j = 0; j < 4; ++j) {
      int ncol = n0 + rn + j * 16 + lr;
      float bv = bias[ncol];
      for (int rr2 = 0; rr2 < 4; ++rr2) {
        float v = acc[i][j][rr2] + bv;
        if (ACT == 1) v = gelu_f(v);
        size_t off = (size_t)(mrow + rr2) * N + ncol;
        if (RES) v += res[off];
        if (OUTF32) ((float*)out)[off] = v;
        else        ((u16*)out)[off] = f2u(v);
      }
    }
  }
}

// ---------------------------------------------------------------------------
// Window attention via MFMA (16x16x32 bf16, same verified fragment maps as
// gemm_kernel). One block per (window, head); 4 waves, each owns 16 Q-rows.
//   QK^T: A=q_lds[row][d], B(Wt-layout)=k_lds[token][d]; K=48 zero-padded to 64.
//   softmax: D row=q*4+reg -> per-reg max/sum + shfl_xor over quad's 16 lanes.
//   PV:   A=p_lds[row][token] (bf16 P), B(Wt-layout)=vt_lds[d][token].
//   O scale 1/l stays in-register (PV D-row mapping == softmax row mapping).
// LDS stride 72 u16 (144B): fragment b128 reads across 16 rows are 2-way on
// banks (free, m136). Total LDS 34.6KB -> 4 blocks/CU.
// ---------------------------------------------------------------------------
__global__ __launch_bounds__(256) void attn_kernel(const u16* __restrict__ qkv,
                                                   u16* __restrict__ attn_out) {
  __shared__ __align__(16) u16 q_lds[64][72];
  __shared__ __align__(16) u16 k_lds[64][72];
  __shared__ __align__(16) u16 vt_lds[48][72];
  __shared__ __align__(16) u16 p_lds[64][72];
  int tid = threadIdx.x;
  int win = blockIdx.x >> 3, head = blockIdx.x & 7;
  const u16* base = qkv + (size_t)win * 64 * N3 + head * HD;

  // stage q,k: 2 matrices x 64 rows x 6 vec8-chunks = 768 chunks
  for (int c = tid; c < 768; c += 256) {
    int s = c / 384, rem = c - s * 384;
    int n = rem / 6, dc = rem - n * 6;
    u16x8 val = *(const u16x8*)(base + (size_t)n * N3 + s * C_ + dc * 8);
    u16* dst = (s == 0) ? &q_lds[n][dc * 8] : &k_lds[n][dc * 8];
    *(u16x8*)dst = val;
  }
  // zero-pad d=48..63 of q,k: 2 x 64 x 2 chunks = 256 (one per thread)
  {
    int s = tid >> 7, rem = tid & 127;
    int n = rem >> 1, dc = 6 + (rem & 1);
    const u16x8 z = {0, 0, 0, 0, 0, 0, 0, 0};
    u16* dst = (s == 0) ? &q_lds[n][dc * 8] : &k_lds[n][dc * 8];
    *(u16x8*)dst = z;
  }
  // stage v transposed: vt[d][token], 3072 scalar writes
  for (int idx = tid; idx < 3072; idx += 256) {
    int n = idx / 48, d = idx - n * 48;
    vt_lds[d][n] = base[(size_t)n * N3 + 2 * C_ + d];
  }
  __syncthreads();

  int lane = tid & 63, wv = tid >> 6;
  int lr = lane & 15, q = lane >> 4;
  int row0 = wv * 16;                       // wave's 16 output rows
  const floatx4 zero4 = {0.f, 0.f, 0.f, 0.f};

  // ---- QK^T: S[16x64] per wave ----
  floatx4 accS[4];
#pragma unroll
  for (int j = 0; j < 4; ++j) accS[j] = zero4;
#pragma unroll
  for (int ks = 0; ks < 2; ++ks) {
    bf16x8 fa = *(const bf16x8*)&q_lds[row0 + lr][ks * 32 + q * 8];
#pragma unroll
    for (int j = 0; j < 4; ++j) {
      bf16x8 fb = *(const bf16x8*)&k_lds[j * 16 + lr][ks * 32 + q * 8];
      accS[j] = __builtin_amdgcn_mfma_f32_16x16x32_bf16(fa, fb, accS[j], 0, 0, 0);
    }
  }

  // ---- softmax (rows row0+q*4+rr; lane holds cols j*16+lr) ----
  const float scale = 0.14433756729740643f;  // 48^-0.5
  float li[4], pS[4][4];
#pragma unroll
  for (int rr = 0; rr < 4; ++rr) {
    float m = fmaxf(fmaxf(accS[0][rr], accS[1][rr]), fmaxf(accS[2][rr], accS[3][rr]));
#pragma unroll
    for (int off = 1; off < 16; off <<= 1) m = fmaxf(m, __shfl_xor(m, off, 64));
    float l = 0.f;
#pragma unroll
    for (int j = 0; j < 4; ++j) {
      float e = __expf((accS[j][rr] - m) * scale);
      pS[j][rr] = e; l += e;
    }
#pragma unroll
    for (int off = 1; off < 16; off <<= 1) l += __shfl_xor(l, off, 64);
    li[rr] = 1.0f / l;
  }
  // write P (bf16) for PV A-operand
#pragma unroll
  for (int j = 0; j < 4; ++j)
#pragma unroll
    for (int rr = 0; rr < 4; ++rr)
      p_lds[row0 + q * 4 + rr][j * 16 + lr] = f2u(pS[j][rr]);
  __syncthreads();

  // ---- PV: O[16x48] = P[16x64] @ V[64x48] ----
  floatx4 accO[3];
#pragma unroll
  for (int nt = 0; nt < 3; ++nt) accO[nt] = zero4;
#pragma unroll
  for (int ks = 0; ks < 2; ++ks) {
    bf16x8 fa = *(const bf16x8*)&p_lds[row0 + lr][ks * 32 + q * 8];
#pragma unroll
    for (int nt = 0; nt < 3; ++nt) {
      bf16x8 fb = *(const bf16x8*)&vt_lds[nt * 16 + lr][ks * 32 + q * 8];
      accO[nt] = __builtin_amdgcn_mfma_f32_16x16x32_bf16(fa, fb, accO[nt], 0, 0, 0);
    }
  }
  // store: row=row0+q*4+rr (matches li), d=nt*16+lr
#pragma unroll
  for (int nt = 0; nt < 3; ++nt)
#pragma unroll
    for (int rr = 0; rr < 4; ++rr) {
      int r = row0 + q * 4 + rr;
      attn_out[(size_t)(win * 64 + r) * C_ + head * HD + nt * 16 + lr] =
          f2u(accO[nt][rr] * li[rr]);
    }
}

// ---------------------------------------------------------------------------
// LayerNorm2 (token layout, fp32 input from xc): one wave per row, 4 rows/block.
// ---------------------------------------------------------------------------
__global__ __launch_bounds__(256) void ln2_kernel(const float* __restrict__ xc,
                                                  const float* __restrict__ g,
                                                  const float* __restrict__ bta,
                                                  u16* __restrict__ out) {
  int tid = threadIdx.x;
  int row = blockIdx.x * 4 + (tid >> 6);
  int lane = tid & 63;
  const float* xr = xc + (size_t)row * C_;
  float v[6];
  float sm = 0.f, sq = 0.f;
  for (int i = 0; i < 6; ++i) {
    v[i] = xr[i * 64 + lane];
    sm += v[i]; sq += v[i] * v[i];
  }
  for (int off = 32; off > 0; off >>= 1) { sm += __shfl_down(sm, off, 64); sq += __shfl_down(sq, off, 64); }
  sm = __shfl(sm, 0, 64); sq = __shfl(sq, 0, 64);
  float m = sm / (float)C_;
  float rstd = rsqrtf(sq / (float)C_ - m * m + 1e-5f);
  u16* orow = out + (size_t)row * C_;
  for (int i = 0; i < 6; ++i) {
    int ch = i * 64 + lane;
    orow[ch] = f2u((v[i] - m) * rstd * g[ch] + bta[ch]);
  }
}

// ---------------------------------------------------------------------------
// Final (per chunk): token layout fp32 -> (C,H,W) fp32 with window reverse +
// roll(+4,+4). Two passes of 192 channels (fp32 LDS tile fits 64 KB).
// Diagnostic sentinels: NaN -> 777, Inf -> 888.
// ---------------------------------------------------------------------------
__global__ __launch_bounds__(256) void permute_kernel(const float* __restrict__ fin,
                                                      float* __restrict__ out) {
  __shared__ float tile[64][194];
  int tid = threadIdx.x;
  int bb = blockIdx.x >> 6, h = blockIdx.x & 63;   // local batch, rolled row
  int h0 = (h + 4) & 63;
  int wb = h >> 3, rr = h & 7;
  for (int half = 0; half < 2; ++half) {
    int c0 = half * 192;
    __syncthreads();
    for (int i = 0; i < 48; ++i) {
      int idx = i * 256 + tid;            // 0..12287
      int w = idx / 192, cl = idx - w * 192;
      int t = ((bb * 64 + wb * 8 + (w >> 3)) << 6) + (rr << 3) + (w & 7);
      tile[w][cl] = fin[(size_t)t * C_ + c0 + cl];
    }
    __syncthreads();
    for (int i = 0; i < 48; ++i) {
      int idx = i * 256 + tid;
      int cl = idx / 64, w = idx & 63;    // cl 0..191
      int w0 = (w + 4) & 63;
      float v = tile[w][cl];
      if (isnan(v)) v = 777.0f;           // NaN sentinel
      else if (isinf(v)) v = 888.0f;      // Inf sentinel
      size_t o = ((size_t)(bb * C_ + c0 + cl) << 12) + (h0 << 6) + w0;
      out[o] = v;
    }
  }
}

// ---------------------------------------------------------------------------
// fp32 inputs, fp32 output. Chunked by batch; chunk count auto-selected at
// runtime: smallest NCHUNK in {2,4,8} whose workspace footprint fits ws_size.
// Footprint = 3.4 MB weights + ctok*6144 B. NCHUNK=2 -> ~205 MB (verified fit).
// d_out (fp32) doubles as xc scratch: chunk's token range == NCHW flat range.
// ---------------------------------------------------------------------------
extern "C" void kernel_launch(void* const* d_in, const int* in_sizes, int n_in,
                              void* d_out, int out_size, void* d_ws, size_t ws_size,
                              hipStream_t stream) {
  const float* x      = (const float*)d_in[0];
  const float* n1g    = (const float*)d_in[1];
  const float* n1b    = (const float*)d_in[2];
  const float* qkv_w  = (const float*)d_in[3];
  const float* qkv_b  = (const float*)d_in[4];
  const float* proj_w = (const float*)d_in[5];
  const float* proj_b = (const float*)d_in[6];
  const float* n2g    = (const float*)d_in[7];
  const float* n2b    = (const float*)d_in[8];
  const float* w1     = (const float*)d_in[9];
  const float* b1     = (const float*)d_in[10];
  const float* w2     = (const float*)d_in[11];
  const float* b2     = (const float*)d_in[12];
  float* outp = (float*)d_out;

  const size_t wbytes = ((size_t)N3 * C_ + (size_t)C_ * C_ +
                         (size_t)CHID * C_ + (size_t)C_ * CHID) * 2;  // 3.46 MB
  int nchunk = 8;
  for (int cand = 2; cand <= 8; cand *= 2) {
    size_t need = wbytes + (size_t)(TOK / cand) * 6144;
    if (need <= ws_size) { nchunk = cand; break; }
  }
  const int bpc  = B_ / nchunk;       // batches per chunk
  const int ctok = TOK / nchunk;      // tokens per chunk
  const int cwin = ctok / 64;         // windows per chunk

  char* ws = (char*)d_ws;
  size_t off = 0;
  u16* wT_qkv  = (u16*)(ws + off); off += (size_t)N3   * C_   * 2;
  u16* wT_proj = (u16*)(ws + off); off += (size_t)C_   * C_   * 2;
  u16* wT_w1   = (u16*)(ws + off); off += (size_t)CHID * C_   * 2;
  u16* wT_w2   = (u16*)(ws + off); off += (size_t)C_   * CHID * 2;
  u16*   W1 = (u16*)(ws + off);   off += (size_t)ctok * C_   * 2;  // wins / ln2out
  u16*   W2 = (u16*)(ws + off);   off += (size_t)ctok * CHID * 2;  // qkv / hidden
  u16*   W3 = (u16*)(ws + off);   off += (size_t)ctok * C_   * 2;  // attn_out
  float* W4 = (float*)(ws + off); off += (size_t)ctok * C_   * 4;  // mlp2out+res

  transpose_kernel<<<dim3(C_ / 32, N3 / 32), 256, 0, stream>>>(qkv_w, wT_qkv, C_, N3);
  transpose_kernel<<<dim3(C_ / 32, C_ / 32), 256, 0, stream>>>(proj_w, wT_proj, C_, C_);
  transpose_kernel<<<dim3(C_ / 32, CHID / 32), 256, 0, stream>>>(w1, wT_w1, C_, CHID);
  transpose_kernel<<<dim3(CHID / 32, C_ / 32), 256, 0, stream>>>(w2, wT_w2, CHID, C_);

  for (int c = 0; c < nchunk; ++c) {
    size_t xelem = (size_t)c * bpc * C_ * H_ * W_;  // chunk's NCHW elem offset
    size_t toff  = (size_t)c * ctok * C_;           // chunk's token elem offset (== xelem)

    // 1. roll + window partition + LN1: fp32 x -> bf16 wins
    ln1_kernel<<<bpc * H_, 256, 0, stream>>>(x + xelem, n1g, n1b, W1);
    // 2. qkv GEMM (bf16 out)
    gemm_kernel<0, false, false><<<dim3(ctok / 128, N3 / 128), 256, 0, stream>>>(
        W1, wT_qkv, qkv_b, nullptr, W2, ctok, N3, C_);
    // 3. attention (bf16 out, MFMA)
    attn_kernel<<<cwin * 8, 256, 0, stream>>>(W2, W3);
    // 4. proj -> xc fp32 (in d_out)
    gemm_kernel<0, false, true><<<dim3(ctok / 128, C_ / 128), 256, 0, stream>>>(
        W3, wT_proj, proj_b, nullptr, outp + toff, ctok, C_, C_);
    // 5. LN2 (fp32 in, bf16 out)
    ln2_kernel<<<ctok / 4, 256, 0, stream>>>(outp + toff, n2g, n2b, W1);
    // 6. MLP1 + gelu (bf16 out)
    gemm_kernel<1, false, false><<<dim3(ctok / 128, CHID / 128), 256, 0, stream>>>(
        W1, wT_w1, b1, nullptr, W2, ctok, CHID, C_);
    // 7. MLP2 + residual(xc fp32) -> fp32
    gemm_kernel<0, true, true><<<dim3(ctok / 128, C_ / 128), 256, 0, stream>>>(
        W2, wT_w2, b2, outp + toff, W4, ctok, C_, CHID);
    // 8. window reverse + roll back -> final fp32 output for this chunk
    permute_kernel<<<bpc * H_, 256, 0, stream>>>(W4, outp + xelem);
  }
}

// Round 15
// 859.591 us; speedup vs baseline: 1.7545x; 1.0348x over previous
//
#include <hip/hip_runtime.h>
#include <hip/hip_bf16.h>

typedef unsigned short u16;
typedef __bf16 bf16x8 __attribute__((ext_vector_type(8)));
typedef float  floatx4 __attribute__((ext_vector_type(4)));
typedef u16    u16x8   __attribute__((ext_vector_type(8)));

#define B_    16
#define C_    384
#define H_    64
#define W_    64
#define TOK   65536      // B*H*W tokens
#define N3    1152       // 3*C
#define CHID  1536       // 4*C
#define HD    48         // head dim

__device__ __forceinline__ float u2f(u16 u) { return __uint_as_float(((unsigned)u) << 16); }
__device__ __forceinline__ u16   f2u(float f) { __bf16 b = (__bf16)f; return *reinterpret_cast<u16*>(&b); }
__device__ __forceinline__ float gelu_f(float v) { return 0.5f * v * (1.0f + erff(v * 0.70710678118654752f)); }

// Async global->LDS, 16B per lane. LDS dest is wave-uniform base + lane*16
// (m104/m108); global src is per-lane.
__device__ __forceinline__ void gload_lds16(const u16* g, u16* l) {
  __builtin_amdgcn_global_load_lds(
      (const __attribute__((address_space(1))) void*)g,
      (__attribute__((address_space(3))) void*)l,
      16, 0, 0);
}

// ---------------------------------------------------------------------------
// roll(-4,-4) + window partition + LayerNorm1 (fp32 input).
// Token layout: t = (b_local*64 + (h/8)*8 + (w/8))*64 + (h%8)*8 + (w%8),
// h/w in rolled coords; rolled (h,w) reads original ((h+4)%64,(w+4)%64).
// grid = bpc*64; blockIdx>>6 = local batch, &63 = rolled row.
// ---------------------------------------------------------------------------
__global__ __launch_bounds__(256) void ln1_kernel(const float* __restrict__ x,
                                                  const float* __restrict__ g,
                                                  const float* __restrict__ bta,
                                                  u16* __restrict__ wins) {
  __shared__ u16 tile[64][C_ + 2];
  __shared__ float psum[4][64], psq[4][64], mean_s[64], rstd_s[64];
  int tid = threadIdx.x;
  int bb = blockIdx.x >> 6;        // local batch
  int h  = blockIdx.x & 63;        // rolled row
  int h0 = (h + 4) & 63;           // original row
  for (int i = 0; i < 96; ++i) {
    int idx = i * 256 + tid;
    int ch = idx >> 6, wr = idx & 63;
    int w0 = (wr + 4) & 63;
    size_t xi = ((size_t)(bb * C_ + ch) << 12) + (h0 << 6) + w0;
    tile[wr][ch] = f2u(x[xi]);
  }
  __syncthreads();
  {
    int s = tid >> 6, p = tid & 63;
    float sm = 0.f, sq = 0.f;
    for (int ii = 0; ii < 96; ++ii) {
      float v = u2f(tile[p][s * 96 + ii]);
      sm += v; sq += v * v;
    }
    psum[s][p] = sm; psq[s][p] = sq;
  }
  __syncthreads();
  if (tid < 64) {
    float m  = psum[0][tid] + psum[1][tid] + psum[2][tid] + psum[3][tid];
    float q2 = psq[0][tid] + psq[1][tid] + psq[2][tid] + psq[3][tid];
    m /= (float)C_;
    float var = q2 / (float)C_ - m * m;
    mean_s[tid] = m;
    rstd_s[tid] = rsqrtf(var + 1e-5f);
  }
  __syncthreads();
  int wb = h >> 3, rr = h & 7;
  for (int i = 0; i < 96; ++i) {
    int idx = i * 256 + tid;
    int pos = idx / C_, ch = idx - pos * C_;
    float v = u2f(tile[pos][ch]);
    float y = (v - mean_s[pos]) * rstd_s[pos] * g[ch] + bta[ch];
    int t = ((bb * 64 + wb * 8 + (pos >> 3)) << 6) + (rr << 3) + (pos & 7);
    wins[(size_t)t * C_ + ch] = f2u(y);
  }
}

// ---------------------------------------------------------------------------
// Weight transpose + bf16 cast: in fp32 (K x N) -> out bf16 (N x K).
// LDS-tiled 32x32 so both global read and write are contiguous.
// ---------------------------------------------------------------------------
__global__ __launch_bounds__(256) void transpose_kernel(const float* __restrict__ in,
                                                        u16* __restrict__ out,
                                                        int K, int N) {
  __shared__ u16 t[32][33];
  int k0 = blockIdx.x * 32, n0 = blockIdx.y * 32;
  int tid = threadIdx.x;
  int r = tid >> 3, c4 = (tid & 7) * 4;
  for (int i = 0; i < 4; ++i)
    t[r][c4 + i] = f2u(in[(size_t)(k0 + r) * N + n0 + c4 + i]);
  __syncthreads();
  for (int i = 0; i < 4; ++i)
    out[(size_t)(n0 + r) * K + k0 + c4 + i] = t[c4 + i][r];
}

// ---------------------------------------------------------------------------
// MFMA GEMM, double-buffered (T3-minimum 2-phase): out = act(A@Bt^T+bias)(+res).
// 128x128 tile / block, 4 waves each 64x64 via 4x4 grid of 16x16x32 bf16 MFMA.
// Per K-step: issue next tile's global_load_lds into buf[nxt] FIRST, then
// ds_read+MFMA from buf[cur], then ONE __syncthreads (its vmcnt(0) drain waits
// on loads that had the whole compute phase as head start). Mechanism: hide
// ~900cyc HBM latency (m126) under compute -- targets measured MfmaUtil=13%
// latency-bound regime. Race-safe: buf[nxt] last read before previous barrier.
// Verified layouts (m89/m91/m118): A[m=lane&15][k=quad*8+j],
// B[k=quad*8+j][n=lane&15], D col=lane&15, row=quad*4+reg.
// ---------------------------------------------------------------------------
template<int ACT, bool RES, bool OUTF32>
__global__ __launch_bounds__(256) void gemm_kernel(const u16* __restrict__ A,
                                                   const u16* __restrict__ Bt,
                                                   const float* __restrict__ bias,
                                                   const float* __restrict__ res,
                                                   void* __restrict__ out,
                                                   int M, int N, int K) {
  __shared__ __align__(16) u16 As[2][128][32];
  __shared__ __align__(16) u16 Bs[2][128][32];
  int tid = threadIdx.x;
  int m0 = blockIdx.x * 128, n0 = blockIdx.y * 128;
  int lane = tid & 63, wv = tid >> 6;
  int rm = (wv >> 1) * 64, rn = (wv & 1) * 64;
  int lr = lane & 15, q = lane >> 4;
  const floatx4 zero = {0.f, 0.f, 0.f, 0.f};
  floatx4 acc[4][4];
  for (int i = 0; i < 4; ++i) for (int j = 0; j < 4; ++j) acc[i][j] = zero;

  // Staging map: 512 chunks of 16B per matrix per K-step. Wave wv, issue s
  // covers chunks [wv*128 + s*64, +64); lane l -> chunk c = that + l.
  // Chunk c -> row r = c>>2, k-part kp = c&3 (8 u16 each).
  int c1 = wv * 128 + lane;             // issue-0 chunk for this thread
  int r1 = c1 >> 2, kp1 = c1 & 3;
  int c2 = c1 + 64;                     // issue-1 chunk
  int r2 = c2 >> 2, kp2 = c2 & 3;
  const u16* gA1 = A  + (size_t)(m0 + r1) * K + kp1 * 8;
  const u16* gA2 = A  + (size_t)(m0 + r2) * K + kp2 * 8;
  const u16* gB1 = Bt + (size_t)(n0 + r1) * K + kp1 * 8;
  const u16* gB2 = Bt + (size_t)(n0 + r2) * K + kp2 * 8;
  u16* lA1 = &As[0][0][0] + wv * 1024;  // wave-uniform LDS bases (u16 units)
  u16* lB1 = &Bs[0][0][0] + wv * 1024;  // buffer b: +b*4096

  // prologue: stage K-step 0 into buffer 0
  gload_lds16(gA1, lA1);
  gload_lds16(gA2, lA1 + 512);
  gload_lds16(gB1, lB1);
  gload_lds16(gB2, lB1 + 512);
  __syncthreads();

  int cur = 0;
  for (int k0 = 0; k0 < K; k0 += 32) {
    int nxt = cur ^ 1;
    if (k0 + 32 < K) {                  // issue next tile's loads FIRST
      int kn = k0 + 32;
      gload_lds16(gA1 + kn, lA1 + nxt * 4096);
      gload_lds16(gA2 + kn, lA1 + nxt * 4096 + 512);
      gload_lds16(gB1 + kn, lB1 + nxt * 4096);
      gload_lds16(gB2 + kn, lB1 + nxt * 4096 + 512);
    }
    bf16x8 fa[4], fb[4];
    for (int i = 0; i < 4; ++i) fa[i] = *(const bf16x8*)&As[cur][rm + i * 16 + lr][q * 8];
    for (int j = 0; j < 4; ++j) fb[j] = *(const bf16x8*)&Bs[cur][rn + j * 16 + lr][q * 8];
    for (int i = 0; i < 4; ++i)
      for (int j = 0; j < 4; ++j)
        acc[i][j] = __builtin_amdgcn_mfma_f32_16x16x32_bf16(fa[i], fb[j], acc[i][j], 0, 0, 0);
    __syncthreads();                    // drains vmcnt -> buf[nxt] ready; buf[cur] reads done
    cur = nxt;
  }
  for (int i = 0; i < 4; ++i) {
    int mrow = m0 + rm + i * 16 + q * 4;
    for (int j = 0; j < 4; ++j) {
      int ncol = n0 + rn + j * 16 + lr;
      float bv = bias[ncol];
      for (int rr2 = 0; rr2 < 4; ++rr2) {
        float v = acc[i][j][rr2] + bv;
        if (ACT == 1) v = gelu_f(v);
        size_t off = (size_t)(mrow + rr2) * N + ncol;
        if (RES) v += res[off];
        if (OUTF32) ((float*)out)[off] = v;
        else        ((u16*)out)[off] = f2u(v);
      }
    }
  }
}

// ---------------------------------------------------------------------------
// Window attention via MFMA (16x16x32 bf16, same verified fragment maps as
// gemm_kernel). One block per (window, head); 4 waves, each owns 16 Q-rows.
//   QK^T: A=q_lds[row][d], B(Wt-layout)=k_lds[token][d]; K=48 zero-padded to 64.
//   softmax: D row=q*4+reg -> per-reg max/sum + shfl_xor over quad's 16 lanes.
//   PV:   A=p_lds[row][token] (bf16 P), B(Wt-layout)=vt_lds[d][token].
//   O scale 1/l stays in-register (PV D-row mapping == softmax row mapping).
// LDS stride 72 u16 (144B): fragment b128 reads across 16 rows are 2-way on
// banks (free, m136). Total LDS 34.6KB -> 4 blocks/CU.
// ---------------------------------------------------------------------------
__global__ __launch_bounds__(256) void attn_kernel(const u16* __restrict__ qkv,
                                                   u16* __restrict__ attn_out) {
  __shared__ __align__(16) u16 q_lds[64][72];
  __shared__ __align__(16) u16 k_lds[64][72];
  __shared__ __align__(16) u16 vt_lds[48][72];
  __shared__ __align__(16) u16 p_lds[64][72];
  int tid = threadIdx.x;
  int win = blockIdx.x >> 3, head = blockIdx.x & 7;
  const u16* base = qkv + (size_t)win * 64 * N3 + head * HD;

  // stage q,k: 2 matrices x 64 rows x 6 vec8-chunks = 768 chunks
  for (int c = tid; c < 768; c += 256) {
    int s = c / 384, rem = c - s * 384;
    int n = rem / 6, dc = rem - n * 6;
    u16x8 val = *(const u16x8*)(base + (size_t)n * N3 + s * C_ + dc * 8);
    u16* dst = (s == 0) ? &q_lds[n][dc * 8] : &k_lds[n][dc * 8];
    *(u16x8*)dst = val;
  }
  // zero-pad d=48..63 of q,k: 2 x 64 x 2 chunks = 256 (one per thread)
  {
    int s = tid >> 7, rem = tid & 127;
    int n = rem >> 1, dc = 6 + (rem & 1);
    const u16x8 z = {0, 0, 0, 0, 0, 0, 0, 0};
    u16* dst = (s == 0) ? &q_lds[n][dc * 8] : &k_lds[n][dc * 8];
    *(u16x8*)dst = z;
  }
  // stage v transposed: vt[d][token], 3072 scalar writes
  for (int idx = tid; idx < 3072; idx += 256) {
    int n = idx / 48, d = idx - n * 48;
    vt_lds[d][n] = base[(size_t)n * N3 + 2 * C_ + d];
  }
  __syncthreads();

  int lane = tid & 63, wv = tid >> 6;
  int lr = lane & 15, q = lane >> 4;
  int row0 = wv * 16;                       // wave's 16 output rows
  const floatx4 zero4 = {0.f, 0.f, 0.f, 0.f};

  // ---- QK^T: S[16x64] per wave ----
  floatx4 accS[4];
#pragma unroll
  for (int j = 0; j < 4; ++j) accS[j] = zero4;
#pragma unroll
  for (int ks = 0; ks < 2; ++ks) {
    bf16x8 fa = *(const bf16x8*)&q_lds[row0 + lr][ks * 32 + q * 8];
#pragma unroll
    for (int j = 0; j < 4; ++j) {
      bf16x8 fb = *(const bf16x8*)&k_lds[j * 16 + lr][ks * 32 + q * 8];
      accS[j] = __builtin_amdgcn_mfma_f32_16x16x32_bf16(fa, fb, accS[j], 0, 0, 0);
    }
  }

  // ---- softmax (rows row0+q*4+rr; lane holds cols j*16+lr) ----
  const float scale = 0.14433756729740643f;  // 48^-0.5
  float li[4], pS[4][4];
#pragma unroll
  for (int rr = 0; rr < 4; ++rr) {
    float m = fmaxf(fmaxf(accS[0][rr], accS[1][rr]), fmaxf(accS[2][rr], accS[3][rr]));
#pragma unroll
    for (int off = 1; off < 16; off <<= 1) m = fmaxf(m, __shfl_xor(m, off, 64));
    float l = 0.f;
#pragma unroll
    for (int j = 0; j < 4; ++j) {
      float e = __expf((accS[j][rr] - m) * scale);
      pS[j][rr] = e; l += e;
    }
#pragma unroll
    for (int off = 1; off < 16; off <<= 1) l += __shfl_xor(l, off, 64);
    li[rr] = 1.0f / l;
  }
  // write P (bf16) for PV A-operand
#pragma unroll
  for (int j = 0; j < 4; ++j)
#pragma unroll
    for (int rr = 0; rr < 4; ++rr)
      p_lds[row0 + q * 4 + rr][j * 16 + lr] = f2u(pS[j][rr]);
  __syncthreads();

  // ---- PV: O[16x48] = P[16x64] @ V[64x48] ----
  floatx4 accO[3];
#pragma unroll
  for (int nt = 0; nt < 3; ++nt) accO[nt] = zero4;
#pragma unroll
  for (int ks = 0; ks < 2; ++ks) {
    bf16x8 fa = *(const bf16x8*)&p_lds[row0 + lr][ks * 32 + q * 8];
#pragma unroll
    for (int nt = 0; nt < 3; ++nt) {
      bf16x8 fb = *(const bf16x8*)&vt_lds[nt * 16 + lr][ks * 32 + q * 8];
      accO[nt] = __builtin_amdgcn_mfma_f32_16x16x32_bf16(fa, fb, accO[nt], 0, 0, 0);
    }
  }
  // store: row=row0+q*4+rr (matches li), d=nt*16+lr
#pragma unroll
  for (int nt = 0; nt < 3; ++nt)
#pragma unroll
    for (int rr = 0; rr < 4; ++rr) {
      int r = row0 + q * 4 + rr;
      attn_out[(size_t)(win * 64 + r) * C_ + head * HD + nt * 16 + lr] =
          f2u(accO[nt][rr] * li[rr]);
    }
}

// ---------------------------------------------------------------------------
// LayerNorm2 (token layout, fp32 input from xc): one wave per row, 4 rows/block.
// ---------------------------------------------------------------------------
__global__ __launch_bounds__(256) void ln2_kernel(const float* __restrict__ xc,
                                                  const float* __restrict__ g,
                                                  const float* __restrict__ bta,
                                                  u16* __restrict__ out) {
  int tid = threadIdx.x;
  int row = blockIdx.x * 4 + (tid >> 6);
  int lane = tid & 63;
  const float* xr = xc + (size_t)row * C_;
  float v[6];
  float sm = 0.f, sq = 0.f;
  for (int i = 0; i < 6; ++i) {
    v[i] = xr[i * 64 + lane];
    sm += v[i]; sq += v[i] * v[i];
  }
  for (int off = 32; off > 0; off >>= 1) { sm += __shfl_down(sm, off, 64); sq += __shfl_down(sq, off, 64); }
  sm = __shfl(sm, 0, 64); sq = __shfl(sq, 0, 64);
  float m = sm / (float)C_;
  float rstd = rsqrtf(sq / (float)C_ - m * m + 1e-5f);
  u16* orow = out + (size_t)row * C_;
  for (int i = 0; i < 6; ++i) {
    int ch = i * 64 + lane;
    orow[ch] = f2u((v[i] - m) * rstd * g[ch] + bta[ch]);
  }
}

// ---------------------------------------------------------------------------
// Final (per chunk): token layout fp32 -> (C,H,W) fp32 with window reverse +
// roll(+4,+4). Two passes of 192 channels (fp32 LDS tile fits 64 KB).
// Diagnostic sentinels: NaN -> 777, Inf -> 888.
// ---------------------------------------------------------------------------
__global__ __launch_bounds__(256) void permute_kernel(const float* __restrict__ fin,
                                                      float* __restrict__ out) {
  __shared__ float tile[64][194];
  int tid = threadIdx.x;
  int bb = blockIdx.x >> 6, h = blockIdx.x & 63;   // local batch, rolled row
  int h0 = (h + 4) & 63;
  int wb = h >> 3, rr = h & 7;
  for (int half = 0; half < 2; ++half) {
    int c0 = half * 192;
    __syncthreads();
    for (int i = 0; i < 48; ++i) {
      int idx = i * 256 + tid;            // 0..12287
      int w = idx / 192, cl = idx - w * 192;
      int t = ((bb * 64 + wb * 8 + (w >> 3)) << 6) + (rr << 3) + (w & 7);
      tile[w][cl] = fin[(size_t)t * C_ + c0 + cl];
    }
    __syncthreads();
    for (int i = 0; i < 48; ++i) {
      int idx = i * 256 + tid;
      int cl = idx / 64, w = idx & 63;    // cl 0..191
      int w0 = (w + 4) & 63;
      float v = tile[w][cl];
      if (isnan(v)) v = 777.0f;           // NaN sentinel
      else if (isinf(v)) v = 888.0f;      // Inf sentinel
      size_t o = ((size_t)(bb * C_ + c0 + cl) << 12) + (h0 << 6) + w0;
      out[o] = v;
    }
  }
}

// ---------------------------------------------------------------------------
// fp32 inputs, fp32 output. Chunked by batch; chunk count auto-selected at
// runtime: smallest NCHUNK in {2,4,8} whose workspace footprint fits ws_size.
// Footprint = 3.4 MB weights + ctok*6144 B. NCHUNK=2 -> ~205 MB (verified fit).
// d_out (fp32) doubles as xc scratch: chunk's token range == NCHW flat range.
// ---------------------------------------------------------------------------
extern "C" void kernel_launch(void* const* d_in, const int* in_sizes, int n_in,
                              void* d_out, int out_size, void* d_ws, size_t ws_size,
                              hipStream_t stream) {
  const float* x      = (const float*)d_in[0];
  const float* n1g    = (const float*)d_in[1];
  const float* n1b    = (const float*)d_in[2];
  const float* qkv_w  = (const float*)d_in[3];
  const float* qkv_b  = (const float*)d_in[4];
  const float* proj_w = (const float*)d_in[5];
  const float* proj_b = (const float*)d_in[6];
  const float* n2g    = (const float*)d_in[7];
  const float* n2b    = (const float*)d_in[8];
  const float* w1     = (const float*)d_in[9];
  const float* b1     = (const float*)d_in[10];
  const float* w2     = (const float*)d_in[11];
  const float* b2     = (const float*)d_in[12];
  float* outp = (float*)d_out;

  const size_t wbytes = ((size_t)N3 * C_ + (size_t)C_ * C_ +
                         (size_t)CHID * C_ + (size_t)C_ * CHID) * 2;  // 3.46 MB
  int nchunk = 8;
  for (int cand = 2; cand <= 8; cand *= 2) {
    size_t need = wbytes + (size_t)(TOK / cand) * 6144;
    if (need <= ws_size) { nchunk = cand; break; }
  }
  const int bpc  = B_ / nchunk;       // batches per chunk
  const int ctok = TOK / nchunk;      // tokens per chunk
  const int cwin = ctok / 64;         // windows per chunk

  char* ws = (char*)d_ws;
  size_t off = 0;
  u16* wT_qkv  = (u16*)(ws + off); off += (size_t)N3   * C_   * 2;
  u16* wT_proj = (u16*)(ws + off); off += (size_t)C_   * C_   * 2;
  u16* wT_w1   = (u16*)(ws + off); off += (size_t)CHID * C_   * 2;
  u16* wT_w2   = (u16*)(ws + off); off += (size_t)C_   * CHID * 2;
  u16*   W1 = (u16*)(ws + off);   off += (size_t)ctok * C_   * 2;  // wins / ln2out
  u16*   W2 = (u16*)(ws + off);   off += (size_t)ctok * CHID * 2;  // qkv / hidden
  u16*   W3 = (u16*)(ws + off);   off += (size_t)ctok * C_   * 2;  // attn_out
  float* W4 = (float*)(ws + off); off += (size_t)ctok * C_   * 4;  // mlp2out+res

  transpose_kernel<<<dim3(C_ / 32, N3 / 32), 256, 0, stream>>>(qkv_w, wT_qkv, C_, N3);
  transpose_kernel<<<dim3(C_ / 32, C_ / 32), 256, 0, stream>>>(proj_w, wT_proj, C_, C_);
  transpose_kernel<<<dim3(C_ / 32, CHID / 32), 256, 0, stream>>>(w1, wT_w1, C_, CHID);
  transpose_kernel<<<dim3(CHID / 32, C_ / 32), 256, 0, stream>>>(w2, wT_w2, CHID, C_);

  for (int c = 0; c < nchunk; ++c) {
    size_t xelem = (size_t)c * bpc * C_ * H_ * W_;  // chunk's NCHW elem offset
    size_t toff  = (size_t)c * ctok * C_;           // chunk's token elem offset (== xelem)

    // 1. roll + window partition + LN1: fp32 x -> bf16 wins
    ln1_kernel<<<bpc * H_, 256, 0, stream>>>(x + xelem, n1g, n1b, W1);
    // 2. qkv GEMM (bf16 out)
    gemm_kernel<0, false, false><<<dim3(ctok / 128, N3 / 128), 256, 0, stream>>>(
        W1, wT_qkv, qkv_b, nullptr, W2, ctok, N3, C_);
    // 3. attention (bf16 out, MFMA)
    attn_kernel<<<cwin * 8, 256, 0, stream>>>(W2, W3);
    // 4. proj -> xc fp32 (in d_out)
    gemm_kernel<0, false, true><<<dim3(ctok / 128, C_ / 128), 256, 0, stream>>>(
        W3, wT_proj, proj_b, nullptr, outp + toff, ctok, C_, C_);
    // 5. LN2 (fp32 in, bf16 out)
    ln2_kernel<<<ctok / 4, 256, 0, stream>>>(outp + toff, n2g, n2b, W1);
    // 6. MLP1 + gelu (bf16 out)
    gemm_kernel<1, false, false><<<dim3(ctok / 128, CHID / 128), 256, 0, stream>>>(
        W1, wT_w1, b1, nullptr, W2, ctok, CHID, C_);
    // 7. MLP2 + residual(xc fp32) -> fp32
    gemm_kernel<0, true, true><<<dim3(ctok / 128, C_ / 128), 256, 0, stream>>>(
        W2, wT_w2, b2, outp + toff, W4, ctok, C_, CHID);
    // 8. window reverse + roll back -> final fp32 output for this chunk
    permute_kernel<<<bpc * H_, 256, 0, stream>>>(W4, outp + xelem);
  }
}